// Round 11
// baseline (221.498 us; speedup 1.0000x reference)
//
#include <hip/hip_runtime.h>
#include <hip/hip_bf16.h>

#define NRES 512
#define CZ   128
#define CT   64

typedef short bf16x8 __attribute__((ext_vector_type(8)));
typedef float f32x4  __attribute__((ext_vector_type(4)));

#define MFMA16(a,b,c) __builtin_amdgcn_mfma_f32_16x16x32_bf16((a),(b),(c),0,0,0)

__device__ __forceinline__ unsigned short f2bf(float f){
  __hip_bfloat16 h = __float2bfloat16(f);
  return __builtin_bit_cast(unsigned short, h);
}
__device__ __forceinline__ bf16x8 pack8(const float4 a, const float4 b){
  bf16x8 r;
  r[0]=(short)f2bf(a.x); r[1]=(short)f2bf(a.y); r[2]=(short)f2bf(a.z); r[3]=(short)f2bf(a.w);
  r[4]=(short)f2bf(b.x); r[5]=(short)f2bf(b.y); r[6]=(short)f2bf(b.z); r[7]=(short)f2bf(b.w);
  return r;
}

// 16-lane sum via DPP: xor1, xor2 (quad_perm), half-mirror, mirror. Pure VALU.
template<int CTRL>
__device__ __forceinline__ float dppadd(float x){
  int y = __builtin_amdgcn_update_dpp(0, __builtin_bit_cast(int, x), CTRL, 0xF, 0xF, false);
  return x + __builtin_bit_cast(float, y);
}
__device__ __forceinline__ f32x4 reduce16(f32x4 p){
#pragma unroll
  for (int r = 0; r < 4; ++r){
    float v = p[r];
    v = dppadd<0xB1>(v);
    v = dppadd<0x4E>(v);
    v = dppadd<0x141>(v);
    v = dppadd<0x140>(v);
    p[r] = v;
  }
  return p;
}

// ---- weight pre-pack: B-fragments for mfma_f32_16x16x32_bf16 ----
// frag f: lane l, elem j -> B[k = ks*32 + (l>>4)*8 + j][col = nt*16 + (l&15)]
// f  0..15: wq (128x64), nt=f>>2, ks=f&3, scale=0.25 folded in
// f 16..23: wk (64x64),  nt=(f-16)>>1, ks=(f-16)&1
// f 24..31: wv (64x64),  nt=head=(f-24)>>1, ks=(f-24)&1
// f 32..47: wo (64x128), nt=(f-32)>>1, ks=(f-32)&1
__global__ void prep_pack(const float* __restrict__ wq, const float* __restrict__ wk,
                          const float* __restrict__ wv, const float* __restrict__ wo,
                          unsigned short* __restrict__ packed){
  int idx = blockIdx.x * 256 + threadIdx.x;
  if (idx >= 48 * 64) return;
  int f = idx >> 6, lane = idx & 63;
  const float* W; int Ncols, nt, ks; float scale = 1.0f;
  if (f < 16)      { W = wq; Ncols = 64;  nt = f >> 2;        ks = f & 3;        scale = 0.25f; }
  else if (f < 24) { W = wk; Ncols = 64;  nt = (f - 16) >> 1; ks = (f - 16) & 1; }
  else if (f < 32) { W = wv; Ncols = 64;  nt = (f - 24) >> 1; ks = (f - 24) & 1; }
  else             { W = wo; Ncols = 128; nt = (f - 32) >> 1; ks = (f - 32) & 1; }
  int col = nt * 16 + (lane & 15);
  int k0  = ks * 32 + (lane >> 4) * 8;
  unsigned short* dst = packed + (size_t)f * 512 + (size_t)lane * 8;
#pragma unroll
  for (int j = 0; j < 8; ++j)
    dst[j] = f2bf(W[(k0 + j) * Ncols + col] * scale);
}

// Block = 1024 threads (16 waves), 256 pixels of row i. Per-wave code is
// byte-identical to R9 (the 111.9us champion, natural VGPR=64 = the 8-wave/SIMD
// budget); only the block geometry changes so occupancy can reach 32 waves/CU:
// 48KB weight stage shared by 16 waves (staging traffic & barrier /4 per px).
// LDS (69632 B):
//   [0,49152)      48 weight B-frags, frag f at f*1024, lane part at lane*16.
//   [49152,69632)  per-wave O half-buffers: wave w at +w*1280:
//                  16 rows x 40 u16 (80B stride: 64B data + 16B pad; R8-proven
//                  ~0 conflicts, enables single-barrier kernel).
// launch_bounds(1024,8): 8 waves/EU -> k = 8*4/16 = 2 blocks/CU, VGPR cap 64.
// 2 blocks/CU: 139KB LDS <= 160KB, 32 waves/CU = 100% occupancy.
#define WLDS 49152
__launch_bounds__(1024, 8)
__global__ void tpa_main(const float* __restrict__ t, const float* __restrict__ z,
                         const float* __restrict__ mask, const float* __restrict__ bo,
                         const unsigned short* __restrict__ packed,
                         float* __restrict__ out){
  __shared__ __align__(16) char smem[69632];

  const int tid  = threadIdx.x;
  const int lane = tid & 63;
  const int w    = tid >> 6;         // wave 0..15 -> rows [16w,16w+16) of the 256-px tile
  const int cl   = lane & 15;        // A-frag row / C-frag col
  const int g    = lane >> 4;        // k-subgroup / C-frag row-group
  const int b    = blockIdx.x;
  const int i    = b >> 1;           // z-row
  const int jb   = (b & 1) << 8;     // 256-px half-row base
  const int r0   = jb + (w << 4);    // wave's first global pixel row
  const int grow = r0 + cl;          // this lane's A-frag global row

  // -------- stage all 48 weight frags (48KB) global -> LDS, async, linear ----
  // dst = idx*16 = wave-uniform base + lane*16: matches global_load_lds constraint.
#pragma unroll
  for (int it = 0; it < 3; ++it){
    int idx = it * 1024 + tid;
    __builtin_amdgcn_global_load_lds(
        reinterpret_cast<const uint4*>(packed) + idx,
        reinterpret_cast<uint4*>(smem) + idx, 16, 0, 0);
  }

  // -------- z fragments: direct global, eager convert --------
  const float4* zp = reinterpret_cast<const float4*>(z + ((size_t)i * NRES + grow) * CZ);
  bf16x8 za[4];
#pragma unroll
  for (int ks = 0; ks < 4; ++ks){
    float4 p0 = zp[ks * 8 + g * 2 + 0];
    float4 p1 = zp[ks * 8 + g * 2 + 1];
    za[ks] = pack8(p0, p1);
  }

  // -------- t fragments: direct global, eager convert --------
  bf16x8 ta[4][2];
#pragma unroll
  for (int s = 0; s < 4; ++s){
    const float4* tp4 = reinterpret_cast<const float4*>(
        t + (((size_t)s * NRES + i) * NRES + grow) * CT);
    float4 a0 = tp4[g * 2 + 0];
    float4 a1 = tp4[g * 2 + 1];
    float4 a2 = tp4[8 + g * 2 + 0];
    float4 a3 = tp4[8 + g * 2 + 1];
    ta[s][0] = pack8(a0, a1);
    ta[s][1] = pack8(a2, a3);
  }

  const float m0 = mask[0], m1 = mask[1], m2 = mask[2], m3 = mask[3];
  const float msum = m0 + m1 + m2 + m3;
  const float gate = (msum > 0.0f) ? 1.0f : 0.0f;
  const float bias[4] = {1e9f * (m0 - 1.0f), 1e9f * (m1 - 1.0f),
                         1e9f * (m2 - 1.0f), 1e9f * (m3 - 1.0f)};

  __syncthreads();   // weights visible; the ONLY barrier in the kernel

#define LDB(fi) (*reinterpret_cast<const bf16x8*>(smem + (size_t)(fi) * 1024 + (size_t)lane * 16))

  // -------- phase A: Q for all 4 heads --------
  f32x4 qf[4];
#pragma unroll
  for (int h = 0; h < 4; ++h){
    f32x4 q = {0.f, 0.f, 0.f, 0.f};
#pragma unroll
    for (int ks = 0; ks < 4; ++ks) q = MFMA16(za[ks], LDB(h * 4 + ks), q);
    qf[h] = q;
  }

  unsigned short* oh = reinterpret_cast<unsigned short*>(smem + WLDS + w * 1280);

  // -------- phase B: per head K-logits, softmax, V combine; O via half-buffer --------
  bf16x8 oa0, oa1;
#pragma unroll
  for (int h = 0; h < 4; ++h){
    f32x4 lgh[4];
#pragma unroll
    for (int s = 0; s < 4; ++s){
      f32x4 acc = {0.f, 0.f, 0.f, 0.f};
      acc = MFMA16(ta[s][0], LDB(16 + h * 2 + 0), acc);
      acc = MFMA16(ta[s][1], LDB(16 + h * 2 + 1), acc);
      f32x4 p = reduce16(acc * qf[h]);
#pragma unroll
      for (int r = 0; r < 4; ++r) p[r] += bias[s];
      lgh[s] = p;
    }
    f32x4 mx, sum = {0.f, 0.f, 0.f, 0.f};
#pragma unroll
    for (int r = 0; r < 4; ++r)
      mx[r] = fmaxf(fmaxf(lgh[0][r], lgh[1][r]), fmaxf(lgh[2][r], lgh[3][r]));
#pragma unroll
    for (int s = 0; s < 4; ++s){
#pragma unroll
      for (int r = 0; r < 4; ++r) lgh[s][r] = __expf(lgh[s][r] - mx[r]);
      sum += lgh[s];
    }
    f32x4 inv;
#pragma unroll
    for (int r = 0; r < 4; ++r) inv[r] = 1.0f / sum[r];
#pragma unroll
    for (int s = 0; s < 4; ++s) lgh[s] *= inv;

    // O = sum_s a_s * (t_s @ wv_h), combined on C-fragments
    f32x4 of = {0.f, 0.f, 0.f, 0.f};
#pragma unroll
    for (int s = 0; s < 4; ++s){
      f32x4 vacc = {0.f, 0.f, 0.f, 0.f};
      vacc = MFMA16(ta[s][0], LDB(24 + h * 2 + 0), vacc);
      vacc = MFMA16(ta[s][1], LDB(24 + h * 2 + 1), vacc);
      of += lgh[s] * vacc;
    }
    const int h2 = h & 1;
#pragma unroll
    for (int r = 0; r < 4; ++r)
      oh[(g * 4 + r) * 40 + h2 * 16 + cl] = f2bf(of[r]);
    if (h == 1){
      asm volatile("s_waitcnt lgkmcnt(0)" ::: "memory");   // writes done
      oa0 = *reinterpret_cast<const bf16x8*>(oh + cl * 40 + g * 8);
      asm volatile("s_waitcnt lgkmcnt(0)" ::: "memory");   // read landed; buffer free
    }
  }
  asm volatile("s_waitcnt lgkmcnt(0)" ::: "memory");
  oa1 = *reinterpret_cast<const bf16x8*>(oh + cl * 40 + g * 8);

  // -------- phase C: out = O @ wo + bo, gated; direct f32 stores --------
  {
    float* outg = out + ((size_t)i * NRES + r0) * CZ;
#pragma unroll
    for (int nt = 0; nt < 8; ++nt){
      f32x4 acc = {0.f, 0.f, 0.f, 0.f};
      acc = MFMA16(oa0, LDB(32 + nt * 2 + 0), acc);
      acc = MFMA16(oa1, LDB(32 + nt * 2 + 1), acc);
      int col = nt * 16 + cl;
      float bov = bo[col];
#pragma unroll
      for (int r = 0; r < 4; ++r)
        outg[(size_t)((g << 2) + r) * CZ + col] = (acc[r] + bov) * gate;
    }
  }
}

extern "C" void kernel_launch(void* const* d_in, const int* in_sizes, int n_in,
                              void* d_out, int out_size, void* d_ws, size_t ws_size,
                              hipStream_t stream) {
  const float* t    = (const float*)d_in[0];
  const float* z    = (const float*)d_in[1];
  const float* mask = (const float*)d_in[2];
  const float* wq   = (const float*)d_in[3];
  const float* wk   = (const float*)d_in[4];
  const float* wv   = (const float*)d_in[5];
  const float* wo   = (const float*)d_in[6];
  const float* bo   = (const float*)d_in[7];
  unsigned short* packed = (unsigned short*)d_ws;

  hipLaunchKernelGGL(prep_pack, dim3(12), dim3(256), 0, stream, wq, wk, wv, wo, packed);
  hipLaunchKernelGGL(tpa_main, dim3(1024), dim3(1024), 0, stream,
                     t, z, mask, bo, packed, (float*)d_out);
}

// Round 12
// 110.353 us; speedup vs baseline: 2.0072x; 2.0072x over previous
//
#include <hip/hip_runtime.h>
#include <hip/hip_bf16.h>

#define NRES 512
#define CZ   128
#define CT   64

typedef short bf16x8 __attribute__((ext_vector_type(8)));
typedef float f32x4  __attribute__((ext_vector_type(4)));

#define MFMA16(a,b,c) __builtin_amdgcn_mfma_f32_16x16x32_bf16((a),(b),(c),0,0,0)

__device__ __forceinline__ unsigned short f2bf(float f){
  __hip_bfloat16 h = __float2bfloat16(f);
  return __builtin_bit_cast(unsigned short, h);
}
__device__ __forceinline__ bf16x8 pack8(const float4 a, const float4 b){
  bf16x8 r;
  r[0]=(short)f2bf(a.x); r[1]=(short)f2bf(a.y); r[2]=(short)f2bf(a.z); r[3]=(short)f2bf(a.w);
  r[4]=(short)f2bf(b.x); r[5]=(short)f2bf(b.y); r[6]=(short)f2bf(b.z); r[7]=(short)f2bf(b.w);
  return r;
}

// 16-lane sum via DPP: xor1, xor2 (quad_perm), half-mirror, mirror. Pure VALU.
template<int CTRL>
__device__ __forceinline__ float dppadd(float x){
  int y = __builtin_amdgcn_update_dpp(0, __builtin_bit_cast(int, x), CTRL, 0xF, 0xF, false);
  return x + __builtin_bit_cast(float, y);
}
__device__ __forceinline__ f32x4 reduce16(f32x4 p){
#pragma unroll
  for (int r = 0; r < 4; ++r){
    float v = p[r];
    v = dppadd<0xB1>(v);
    v = dppadd<0x4E>(v);
    v = dppadd<0x141>(v);
    v = dppadd<0x140>(v);
    p[r] = v;
  }
  return p;
}

// ---- weight pre-pack: B-fragments for mfma_f32_16x16x32_bf16 ----
// frag f: lane l, elem j -> B[k = ks*32 + (l>>4)*8 + j][col = nt*16 + (l&15)]
// f  0..15: wq (128x64), nt=f>>2, ks=f&3, scale=0.25 folded in
// f 16..23: wk (64x64),  nt=(f-16)>>1, ks=(f-16)&1
// f 24..31: wv (64x64),  nt=head=(f-24)>>1, ks=(f-24)&1
// f 32..47: wo (64x128), nt=(f-32)>>1, ks=(f-32)&1
__global__ void prep_pack(const float* __restrict__ wq, const float* __restrict__ wk,
                          const float* __restrict__ wv, const float* __restrict__ wo,
                          unsigned short* __restrict__ packed){
  int idx = blockIdx.x * 256 + threadIdx.x;
  if (idx >= 48 * 64) return;
  int f = idx >> 6, lane = idx & 63;
  const float* W; int Ncols, nt, ks; float scale = 1.0f;
  if (f < 16)      { W = wq; Ncols = 64;  nt = f >> 2;        ks = f & 3;        scale = 0.25f; }
  else if (f < 24) { W = wk; Ncols = 64;  nt = (f - 16) >> 1; ks = (f - 16) & 1; }
  else if (f < 32) { W = wv; Ncols = 64;  nt = (f - 24) >> 1; ks = (f - 24) & 1; }
  else             { W = wo; Ncols = 128; nt = (f - 32) >> 1; ks = (f - 32) & 1; }
  int col = nt * 16 + (lane & 15);
  int k0  = ks * 32 + (lane >> 4) * 8;
  unsigned short* dst = packed + (size_t)f * 512 + (size_t)lane * 8;
#pragma unroll
  for (int j = 0; j < 8; ++j)
    dst[j] = f2bf(W[(k0 + j) * Ncols + col] * scale);
}

// Block = 256 threads (4 waves), 64 pixels of row i. R9 champion structure,
// ONE deliberate change: amdgpu_waves_per_eu(3,3) pins the allocator at the
// occupancy LDS already enforces (3 blocks/CU = 3 waves/EU), giving a ~170
// VGPR budget. All 24 input float4s load into NAMED registers first, convert
// after -> all loads in flight at once, ONE HBM round trip per wave instead
// of the 4-6 serial trips R9's 64-reg windowing forced.
// LDS (49152 B): [0,49152) 48 weight B-frags (frag f at f*1024, lane at *16);
// after phase A the dead wq region [0,8192) holds per-wave O buffers (w*2048).
__global__ void __launch_bounds__(256)
__attribute__((amdgpu_waves_per_eu(3, 3)))
tpa_main(const float* __restrict__ t, const float* __restrict__ z,
         const float* __restrict__ mask, const float* __restrict__ bo,
         const unsigned short* __restrict__ packed,
         float* __restrict__ out){
  __shared__ __align__(16) char smem[49152];

  const int tid  = threadIdx.x;
  const int lane = tid & 63;
  const int w    = tid >> 6;         // wave 0..3 -> rows [16w,16w+16) of the tile
  const int cl   = lane & 15;        // A-frag row / C-frag col
  const int g    = lane >> 4;        // k-subgroup / C-frag row-group
  const int b    = blockIdx.x;
  const int i    = b >> 3;           // z-row
  const int j0   = (b & 7) << 6;     // pixel-column tile base
  const int r0   = j0 + (w << 4);    // wave's first global pixel row
  const int grow = r0 + cl;          // this lane's A-frag global row

  // -------- stage all 48 weight frags (48KB) global -> LDS, async, linear ----
#pragma unroll
  for (int it = 0; it < 12; ++it){
    int idx = it * 256 + tid;
    __builtin_amdgcn_global_load_lds(
        reinterpret_cast<const uint4*>(packed) + idx,
        reinterpret_cast<uint4*>(smem) + idx, 16, 0, 0);
  }

  // -------- issue ALL 24 input loads into named registers (one round trip) ----
  const float4* zp = reinterpret_cast<const float4*>(z + ((size_t)i * NRES + grow) * CZ);
  float4 zr0 = zp[0*8 + g*2 + 0], zr1 = zp[0*8 + g*2 + 1];
  float4 zr2 = zp[1*8 + g*2 + 0], zr3 = zp[1*8 + g*2 + 1];
  float4 zr4 = zp[2*8 + g*2 + 0], zr5 = zp[2*8 + g*2 + 1];
  float4 zr6 = zp[3*8 + g*2 + 0], zr7 = zp[3*8 + g*2 + 1];

  const float4* tp0 = reinterpret_cast<const float4*>(t + (((size_t)0 * NRES + i) * NRES + grow) * CT);
  const float4* tp1 = reinterpret_cast<const float4*>(t + (((size_t)1 * NRES + i) * NRES + grow) * CT);
  const float4* tp2 = reinterpret_cast<const float4*>(t + (((size_t)2 * NRES + i) * NRES + grow) * CT);
  const float4* tp3 = reinterpret_cast<const float4*>(t + (((size_t)3 * NRES + i) * NRES + grow) * CT);
  float4 t00 = tp0[g*2+0], t01 = tp0[g*2+1], t02 = tp0[8+g*2+0], t03 = tp0[8+g*2+1];
  float4 t10 = tp1[g*2+0], t11 = tp1[g*2+1], t12 = tp1[8+g*2+0], t13 = tp1[8+g*2+1];
  float4 t20 = tp2[g*2+0], t21 = tp2[g*2+1], t22 = tp2[8+g*2+0], t23 = tp2[8+g*2+1];
  float4 t30 = tp3[g*2+0], t31 = tp3[g*2+1], t32 = tp3[8+g*2+0], t33 = tp3[8+g*2+1];

  // -------- convert to bf16 fragments (raw regs die here) --------
  bf16x8 za[4];
  za[0] = pack8(zr0, zr1); za[1] = pack8(zr2, zr3);
  za[2] = pack8(zr4, zr5); za[3] = pack8(zr6, zr7);
  bf16x8 ta[4][2];
  ta[0][0] = pack8(t00, t01); ta[0][1] = pack8(t02, t03);
  ta[1][0] = pack8(t10, t11); ta[1][1] = pack8(t12, t13);
  ta[2][0] = pack8(t20, t21); ta[2][1] = pack8(t22, t23);
  ta[3][0] = pack8(t30, t31); ta[3][1] = pack8(t32, t33);

  const float m0 = mask[0], m1 = mask[1], m2 = mask[2], m3 = mask[3];
  const float msum = m0 + m1 + m2 + m3;
  const float gate = (msum > 0.0f) ? 1.0f : 0.0f;
  const float bias[4] = {1e9f * (m0 - 1.0f), 1e9f * (m1 - 1.0f),
                         1e9f * (m2 - 1.0f), 1e9f * (m3 - 1.0f)};

  __syncthreads();   // weight LDS visible

#define LDB(fi) (*reinterpret_cast<const bf16x8*>(smem + (size_t)(fi) * 1024 + (size_t)lane * 16))

  // -------- phase A: Q for all 4 heads (consumes wq frags 0..15) --------
  f32x4 qf[4];
#pragma unroll
  for (int h = 0; h < 4; ++h){
    f32x4 q = {0.f, 0.f, 0.f, 0.f};
#pragma unroll
    for (int ks = 0; ks < 4; ++ks) q = MFMA16(za[ks], LDB(h * 4 + ks), q);
    qf[h] = q;
  }

  __syncthreads();   // all waves done with wq; O may overlay [0,8192)

  unsigned short* o_ws = reinterpret_cast<unsigned short*>(smem + w * 2048);

  // -------- phase B: per head K-logits, softmax, V combine (C-layout) --------
#pragma unroll
  for (int h = 0; h < 4; ++h){
    f32x4 lgh[4];
#pragma unroll
    for (int s = 0; s < 4; ++s){
      f32x4 acc = {0.f, 0.f, 0.f, 0.f};
      acc = MFMA16(ta[s][0], LDB(16 + h * 2 + 0), acc);
      acc = MFMA16(ta[s][1], LDB(16 + h * 2 + 1), acc);
      f32x4 p = reduce16(acc * qf[h]);
#pragma unroll
      for (int r = 0; r < 4; ++r) p[r] += bias[s];
      lgh[s] = p;
    }
    f32x4 mx, sum = {0.f, 0.f, 0.f, 0.f};
#pragma unroll
    for (int r = 0; r < 4; ++r)
      mx[r] = fmaxf(fmaxf(lgh[0][r], lgh[1][r]), fmaxf(lgh[2][r], lgh[3][r]));
#pragma unroll
    for (int s = 0; s < 4; ++s){
#pragma unroll
      for (int r = 0; r < 4; ++r) lgh[s][r] = __expf(lgh[s][r] - mx[r]);
      sum += lgh[s];
    }
    f32x4 inv;
#pragma unroll
    for (int r = 0; r < 4; ++r) inv[r] = 1.0f / sum[r];
#pragma unroll
    for (int s = 0; s < 4; ++s) lgh[s] *= inv;

    // O = sum_s a_s * (t_s @ wv_h), combined on C-fragments
    f32x4 of = {0.f, 0.f, 0.f, 0.f};
#pragma unroll
    for (int s = 0; s < 4; ++s){
      f32x4 vacc = {0.f, 0.f, 0.f, 0.f};
      vacc = MFMA16(ta[s][0], LDB(24 + h * 2 + 0), vacc);
      vacc = MFMA16(ta[s][1], LDB(24 + h * 2 + 1), vacc);
      of += lgh[s] * vacc;
    }
#pragma unroll
    for (int r = 0; r < 4; ++r){
      int row = (g << 2) + r;
      o_ws[row * 64 + ((h * 16 + cl) ^ ((row & 7) << 3))] = (unsigned short)f2bf(of[r]);
    }
  }
  asm volatile("s_waitcnt lgkmcnt(0)" ::: "memory");   // wave-private O complete

  // -------- phase C: out = O @ wo + bo, gated; direct f32 stores --------
  {
    bf16x8 oa[2];
#pragma unroll
    for (int ks = 0; ks < 2; ++ks)
      oa[ks] = *reinterpret_cast<const bf16x8*>(
          o_ws + cl * 64 + ((ks * 32 + g * 8) ^ ((cl & 7) << 3)));

    float* outg = out + ((size_t)i * NRES + r0) * CZ;
#pragma unroll
    for (int nt = 0; nt < 8; ++nt){
      f32x4 acc = {0.f, 0.f, 0.f, 0.f};
      acc = MFMA16(oa[0], LDB(32 + nt * 2 + 0), acc);
      acc = MFMA16(oa[1], LDB(32 + nt * 2 + 1), acc);
      int col = nt * 16 + cl;
      float bov = bo[col];
#pragma unroll
      for (int r = 0; r < 4; ++r)
        outg[(size_t)((g << 2) + r) * CZ + col] = (acc[r] + bov) * gate;
    }
  }
}

extern "C" void kernel_launch(void* const* d_in, const int* in_sizes, int n_in,
                              void* d_out, int out_size, void* d_ws, size_t ws_size,
                              hipStream_t stream) {
  const float* t    = (const float*)d_in[0];
  const float* z    = (const float*)d_in[1];
  const float* mask = (const float*)d_in[2];
  const float* wq   = (const float*)d_in[3];
  const float* wk   = (const float*)d_in[4];
  const float* wv   = (const float*)d_in[5];
  const float* wo   = (const float*)d_in[6];
  const float* bo   = (const float*)d_in[7];
  unsigned short* packed = (unsigned short*)d_ws;

  hipLaunchKernelGGL(prep_pack, dim3(12), dim3(256), 0, stream, wq, wk, wv, wo, packed);
  hipLaunchKernelGGL(tpa_main, dim3(4096), dim3(256), 0, stream,
                     t, z, mask, bo, packed, (float*)d_out);
}